// Round 15
// baseline (3904.974 us; speedup 1.0000x reference)
//
#include <hip/hip_runtime.h>

typedef __attribute__((ext_vector_type(8))) short short8;
typedef __attribute__((ext_vector_type(4))) float floatx4;

#define SEQ 512
#define BS  64
#define HID 1024
#define G4  4096
#define NBLK 128
#define NGRP 4    // batch groups
#define BPG  32   // blocks per group
#define GBS  16   // batch rows per group
#define UPB  32   // hidden units per block

__device__ __forceinline__ unsigned short f2b(float f) {
  union { float f; unsigned u; } v; v.f = f;
  return (unsigned short)((v.u + 0x7FFFu + ((v.u >> 16) & 1u)) >> 16);
}
__device__ __forceinline__ float b2f(unsigned short s) {
  union { unsigned u; float f; } v; v.u = ((unsigned)s) << 16;
  return v.f;
}

// device-coherent (cross-XCD) async global->LDS: aux=17 = SC0|SC1 (proven r4+)
__device__ __forceinline__ void gload_lds16_cc(const void* g, void* l) {
  __builtin_amdgcn_global_load_lds(
      (const __attribute__((address_space(1))) unsigned int*)g,
      (__attribute__((address_space(3))) unsigned int*)l,
      16, 0, 17);
}

// ---- weight transpose+convert: W[1024][4096] f32 -> WT[4096][1024] bf16
__global__ void wtrans(const float* __restrict__ W, short* __restrict__ WT) {
  __shared__ float tile[32][33];
  const int tx = threadIdx.x, ty = threadIdx.y;
  const int n0 = blockIdx.x << 5, k0 = blockIdx.y << 5;
#pragma unroll
  for (int i = 0; i < 32; i += 8)
    tile[ty + i][tx] = W[(size_t)(k0 + ty + i) * G4 + n0 + tx];
  __syncthreads();
#pragma unroll
  for (int i = 0; i < 32; i += 8)
    WT[(size_t)(n0 + ty + i) * 1024 + k0 + tx] = (short)f2b(tile[tx][ty + i]);
}

// ---- f32 -> bf16 convert (x into the shared A buffer)
__global__ __launch_bounds__(256)
void conv_bf16(const float* __restrict__ in, unsigned short* __restrict__ out) {
  const size_t i = ((size_t)blockIdx.x * 256 + threadIdx.x) * 8;
  const floatx4 a = *(const floatx4*)(in + i);
  const floatx4 b = *(const floatx4*)(in + i + 4);
  short8 s;
#pragma unroll
  for (int e = 0; e < 4; ++e) { s[e] = (short)f2b(a[e]); s[4 + e] = (short)f2b(b[e]); }
  *(short8*)(out + i) = s;
}

struct FusedArgs {
  // scan (blocks 0..127): recurrence for chunk [t0,t1) reading bf16 xw
  const unsigned short* xw;
  const short* wt_hi;
  unsigned short* hbuf;    // [2][grp][producer][row][unit] bf16 ping-pong
  float* cbuf;             // [64*1024] f32 persistent cell state
  unsigned int* flags;     // [NBLK] u32 padded to 64B
  float* hs;               // [512][64][1024] f32 output
  unsigned short* hsb;     // shared bf16 buffer: x rows become h rows
  float* h_final;
  float* c_final;
  int t0, t1, wr_final;
  // gemm: bf16 xw for the NEXT chunk -> dst
  const short* A;          // bf16 [Mrows][1024]
  const short* BT;         // WT [4096][1024] bf16
  const float* bias;
  unsigned short* dst;
  int Mrows, genable;
};

// ---- scan body: 8 waves x 512 threads, r11 geometry. NEW: producer-major
// h layout ([producer j][row][unit] = 1KB contiguous per producer) =>
// publish is 1KB contiguous, staging is 1 linear gload_lds per span, K-loop
// span-reads are the canonical conflict-free b128 pattern (no swizzle).
// NEW: per-wave fine-grained handoff — wave w polls only its 4 producers
// and stages their spans immediately (early data streams under late polls).
__device__ __forceinline__ void scan_body(const FusedArgs& p, char* smem) {
  float* gsm = (float*)(smem + 32768);   // [4 gate][16 b][33] f32 = 8448B
  const int tid = threadIdx.x;
  const int wave = tid >> 6, lane = tid & 63;
  const int lr = lane & 15, lh = lane >> 4;
  const int gate = wave >> 1, uh = wave & 1;
  const int blk = blockIdx.x;
  const int g = blk >> 5;                // batch group 0..3
  const int ub_idx = blk & 31;           // producer slot within group
  const int gcol = (gate << 10) + ub_idx * UPB + (uh << 4) + lr;

  // ---- preload B fragments (W_hi, full K): 32 x short8 = 128 regs
  short8 breg[32];
  {
    const short* wp = p.wt_hi + (size_t)gcol * HID + (lh << 3);
#pragma unroll
    for (int kk = 0; kk < 32; ++kk) breg[kk] = *(const short8*)(wp + (kk << 5));
  }

  const int b_loc = tid >> 5, u_loc = tid & 31;   // 512 threads = 16b x 32u
  const int ci = ((g * GBS + b_loc) << 10) + ub_idx * UPB + u_loc;
  float creg = p.cbuf[ci];

  // this wave's 4 producers: 4*wave + (lane&3)
  const unsigned long long fad =
      (unsigned long long)(p.flags + ((size_t)(g * BPG) + (wave << 2) + (lane & 3)) * 16);

  for (int t = p.t0; t < p.t1; ++t) {
    // ---- xw prefetch BEFORE the poll: latency rides under the flag wait
    float xv[4];
#pragma unroll
    for (int r = 0; r < 4; ++r) {
      const size_t rowi = (size_t)(t - p.t0) * BS + g * GBS + (lh << 2) + r;
      xv[r] = b2f(p.xw[rowi * G4 + gcol]);
    }

    // ---- fine-grained barrier-in: each wave waits only its 4 producers
    if (t > 0) {
      unsigned f0;
      for (;;) {
        asm volatile("global_load_dword %0, %1, off sc0 sc1\n\t"
                     "s_waitcnt vmcnt(0)"
                     : "=v"(f0) : "v"(fad) : "memory");
        if (__all(f0 >= (unsigned)t)) break;
        __builtin_amdgcn_s_sleep(1);
      }
    }

    const unsigned short* hb = p.hbuf + (size_t)(t & 1) * (BS * HID) + (size_t)g * GBS * HID;
    unsigned short* hw = p.hbuf + (size_t)((t + 1) & 1) * (BS * HID) + (size_t)g * GBS * HID;

    // ---- stage this wave's 4 producer spans (1KB each, linear)
#pragma unroll
    for (int q = 0; q < 4; ++q) {
      const int pj = (wave << 2) + q;
      gload_lds16_cc(hb + (pj << 9) + (lane << 3), smem + (pj << 10));
    }
    asm volatile("s_waitcnt vmcnt(0)" ::: "memory");
    __builtin_amdgcn_s_barrier();        // all spans resident
    __builtin_amdgcn_sched_barrier(0);

    // ---- K loop: span kk holds k=32kk..32kk+31; conflict-free b128 reads
    floatx4 acc = {0.f, 0.f, 0.f, 0.f};
#pragma unroll
    for (int kk = 0; kk < 32; ++kk) {
      const short8 afr = *(const short8*)(smem + (kk << 10) + (lr << 6) + (lh << 4));
      acc = __builtin_amdgcn_mfma_f32_16x16x32_bf16(afr, breg[kk], acc, 0, 0, 0);
    }

    // ---- gates to gsm (full sums — no kh exchange)
#pragma unroll
    for (int r = 0; r < 4; ++r) {
      const int b = (lh << 2) + r;
      gsm[((gate << 4) + b) * 33 + (uh << 4) + lr] = acc[r] + xv[r];
    }
    __syncthreads();

    // ---- elementwise update + paired coherent publish (1KB contiguous)
    const int o = b_loc * 33 + u_loc;
    const float ig = gsm[o];
    const float fg = gsm[16 * 33 + o];
    const float gg2 = gsm[32 * 33 + o];
    const float og = gsm[48 * 33 + o];
    const float iv = 1.f / (1.f + __expf(-ig));
    const float fv = 1.f / (1.f + __expf(-fg));
    const float gv = tanhf(gg2);
    const float ov = 1.f / (1.f + __expf(-og));
    const float cn = fv * creg + iv * gv;
    creg = cn;
    const float hv = ov * tanhf(cn);
    const unsigned hv16 = (unsigned)f2b(hv);
    {
      const unsigned other = (unsigned)__shfl_xor((int)hv16, 1, 64);
      if ((u_loc & 1) == 0) {
        const unsigned val = (hv16 & 0xFFFFu) | (other << 16);
        const unsigned long long dst = (unsigned long long)
            (hw + ((size_t)ub_idx << 9) + (b_loc << 5) + u_loc);
        asm volatile("global_store_dword %0, %1, off sc0 sc1"
                     :: "v"(dst), "v"(val) : "memory");
      }
    }
    asm volatile("s_waitcnt vmcnt(0)" ::: "memory");  // publish acked
    __syncthreads();                                  // all waves acked
    if (tid == 0) {
      const unsigned long long fdst =
          (unsigned long long)(p.flags + (size_t)blk * 16);
      const unsigned fval = (unsigned)(t + 1);
      asm volatile("global_store_dword %0, %1, off sc0 sc1"
                   :: "v"(fdst), "v"(fval) : "memory");
    }
    // hs (f32 out) + hsb (bf16 A-buffer) writes off the critical path
    {
      const size_t oidx = ((size_t)t * BS + g * GBS + b_loc) * HID + ub_idx * UPB + u_loc;
      p.hs[oidx] = hv;
      p.hsb[oidx] = (unsigned short)hv16;
      if (p.wr_final && t == SEQ - 1) { p.h_final[ci] = hv; p.c_final[ci] = cn; }
    }
  }
  p.cbuf[ci] = creg;
}

// ---- gemm body: 512 threads / 8 waves (4x2 wave grid of 32x64), bf16 A/B,
// 128x128 tile, software-pipelined staging (r10/r11-proven geometry).
__device__ __forceinline__ void gemm_body(const FusedArgs& p, char* smem,
                                          int bi, int gstride) {
  if (!p.genable) return;
  short* Al = (short*)smem;            // [128][40]
  short* Bl = (short*)(smem + 10240);  // [128][40]
  const int tid = threadIdx.x;
  const int wave = tid >> 6, lane = tid & 63;
  const int lr = lane & 15, lh = lane >> 4;
  const int wm = wave >> 1, wn = wave & 1;   // 4x2 waves: 32 rows x 64 cols
  const int nmt = p.Mrows >> 7;
  const int tot = nmt << 5;                  // nmt x 32 tiles of 128x128
  const int srow = tid >> 2, scol = (tid & 3) << 3;   // short8 per thread

  for (int tt = bi; tt < tot; tt += gstride) {
    const int m0 = (tt >> 5) << 7, n0 = (tt & 31) << 7;
    const short* aptr = p.A + (size_t)(m0 + srow) * 1024 + scol;
    const short* bptr = p.BT + (size_t)(n0 + srow) * 1024 + scol;
    floatx4 acc[2][4] = {};
    short8 pa = *(const short8*)aptr;
    short8 pb = *(const short8*)bptr;
    for (int it = 0; it < 32; ++it) {
      __syncthreads();
      *(short8*)&Al[srow * 40 + scol] = pa;
      *(short8*)&Bl[srow * 40 + scol] = pb;
      __syncthreads();
      if (it < 31) {
        pa = *(const short8*)(aptr + ((it + 1) << 5));
        pb = *(const short8*)(bptr + ((it + 1) << 5));
      }
      short8 af[2], bf[4];
#pragma unroll
      for (int mt = 0; mt < 2; ++mt)
        af[mt] = *(const short8*)&Al[(wm * 32 + mt * 16 + lr) * 40 + lh * 8];
#pragma unroll
      for (int nt = 0; nt < 4; ++nt)
        bf[nt] = *(const short8*)&Bl[(wn * 64 + nt * 16 + lr) * 40 + lh * 8];
#pragma unroll
      for (int mt = 0; mt < 2; ++mt)
#pragma unroll
        for (int nt = 0; nt < 4; ++nt)
          acc[mt][nt] = __builtin_amdgcn_mfma_f32_16x16x32_bf16(af[mt], bf[nt], acc[mt][nt], 0, 0, 0);
    }
#pragma unroll
    for (int nt = 0; nt < 4; ++nt) {
      const int gc = n0 + wn * 64 + nt * 16 + lr;
      const float bv = p.bias[gc];
#pragma unroll
      for (int mt = 0; mt < 2; ++mt)
#pragma unroll
        for (int r = 0; r < 4; ++r) {
          const int gr = m0 + wm * 32 + mt * 16 + (lh << 2) + r;
          p.dst[(size_t)gr * G4 + gc] = f2b(acc[mt][nt][r] + bv);
        }
    }
  }
}

// prologue: pure-gemm dispatch, 256 blocks (one per CU)
__global__ __launch_bounds__(512, 2)
void gemm_pre(FusedArgs p) {
  __shared__ __align__(16) char smem[84480];
  gemm_body(p, smem, blockIdx.x, 2 * NBLK);
}

// 256 blocks x 512 threads. LDS 82.5KB forces 1 block/CU:
// scan blocks (0..127) and gemm blocks (128..255) land on different CUs.
__global__ __launch_bounds__(512, 2)
void lstm_fused(FusedArgs p) {
  __shared__ __align__(16) char smem[84480];
  if (blockIdx.x < NBLK) scan_body(p, smem);
  else                   gemm_body(p, smem, blockIdx.x - NBLK, NBLK);
}

extern "C" void kernel_launch(void* const* d_in, const int* in_sizes, int n_in,
                              void* d_out, int out_size, void* d_ws, size_t ws_size,
                              hipStream_t stream) {
  const float* x    = (const float*)d_in[0];
  const float* Wii0 = (const float*)d_in[1];
  const float* Wii  = (const float*)d_in[2];
  const float* Whi  = (const float*)d_in[3];
  const float* bias = (const float*)d_in[4];
  float* out  = (float*)d_out;
  float* hs   = out;
  float* hfin = out + (size_t)SEQ * BS * HID;
  float* cfin = hfin + BS * HID;

  char* ws = (char*)d_ws;
  short* WT0 = (short*)ws;
  short* WT1 = WT0 + (size_t)G4 * 1024;
  short* WTh = WT1 + (size_t)G4 * 1024;
  unsigned short* hbuf = (unsigned short*)(WTh + (size_t)G4 * 1024);
  float* cbuf = (float*)(hbuf + 2 * BS * HID);
  unsigned int* flags = (unsigned int*)(cbuf + BS * HID);   // 128 * 64B
  unsigned short* xb = (unsigned short*)(flags + NBLK * 16); // shared x/h bf16
  char* tail = (char*)(xb + (size_t)SEQ * BS * HID);
  const size_t head = (size_t)(tail - ws);
  const size_t avail = (ws_size > head) ? ws_size - head : 0;
  const size_t perT = (size_t)BS * G4 * 2;   // 512 KiB per timestep (bf16)

  int chunk;
  if      (avail >= 2 * 128 * perT) chunk = 128;
  else if (avail >= 2 * 64  * perT) chunk = 64;
  else if (avail >= 2 * 32  * perT) chunk = 32;
  else                              chunk = 8;
  const size_t chunkBytes = (size_t)chunk * perT;
  unsigned short* xwbuf[2] = { (unsigned short*)tail,
                               (unsigned short*)(tail + chunkBytes) };
  const int nc = SEQ / chunk;

  wtrans<<<dim3(128, 32), dim3(32, 8), 0, stream>>>(Wii0, WT0);
  wtrans<<<dim3(128, 32), dim3(32, 8), 0, stream>>>(Wii, WT1);
  wtrans<<<dim3(128, 32), dim3(32, 8), 0, stream>>>(Whi, WTh);
  conv_bf16<<<dim3((SEQ * BS * HID) / (256 * 8)), dim3(256), 0, stream>>>(x, xb);

  for (int layer = 0; layer < 2; ++layer) {
    hipMemsetAsync(hbuf, 0, 2 * BS * HID * sizeof(unsigned short), stream);
    hipMemsetAsync(cbuf, 0, BS * HID * sizeof(float), stream);
    hipMemsetAsync(flags, 0, NBLK * 16 * sizeof(unsigned int), stream);

    if (layer == 0) {  // prologue: only xw chunk not hidden behind a scan
      FusedArgs pa = {};
      pa.A = (const short*)xb;
      pa.BT = WT0;
      pa.bias = bias;
      pa.dst = xwbuf[0];
      pa.Mrows = chunk * BS;
      pa.genable = 1;
      gemm_pre<<<dim3(2 * NBLK), dim3(512), 0, stream>>>(pa);
    }

    for (int c = 0; c < nc; ++c) {
      FusedArgs fa;
      fa.xw = xwbuf[c & 1];
      fa.wt_hi = WTh;
      fa.hbuf = hbuf;
      fa.cbuf = cbuf;
      fa.flags = flags;
      fa.hs = hs;
      fa.hsb = xb;
      fa.h_final = layer ? hfin : nullptr;
      fa.c_final = layer ? cfin : nullptr;
      fa.t0 = c * chunk;
      fa.t1 = (c + 1) * chunk;
      fa.wr_final = layer;
      // producer: bf16 xw for the next chunk (wraps to next layer's first).
      fa.bias = bias;
      fa.dst = xwbuf[(c + 1) & 1];
      fa.Mrows = chunk * BS;
      const int nxt = ((c + 1) % nc) * chunk * BS;
      fa.A = (const short*)(xb + (size_t)nxt * HID);
      fa.BT = (layer == 0 && c < nc - 1) ? WT0 : WT1;
      fa.genable = !(layer == 1 && c == nc - 1);
      void* args[] = { &fa };
      hipLaunchCooperativeKernel(reinterpret_cast<const void*>(&lstm_fused),
                                 dim3(2 * NBLK), dim3(512), args, 0u, stream);
    }
  }
}

// Round 16
// 3791.702 us; speedup vs baseline: 1.0299x; 1.0299x over previous
//
#include <hip/hip_runtime.h>

typedef __attribute__((ext_vector_type(8))) short short8;
typedef __attribute__((ext_vector_type(4))) float floatx4;

#define SEQ 512
#define BS  64
#define HID 1024
#define G4  4096
#define NBLK 128
#define NGRP 4    // batch groups
#define BPG  32   // blocks per group
#define GBS  16   // batch rows per group
#define UPB  32   // hidden units per block

__device__ __forceinline__ unsigned short f2b(float f) {
  union { float f; unsigned u; } v; v.f = f;
  return (unsigned short)((v.u + 0x7FFFu + ((v.u >> 16) & 1u)) >> 16);
}
__device__ __forceinline__ float b2f(unsigned short s) {
  union { unsigned u; float f; } v; v.u = ((unsigned)s) << 16;
  return v.f;
}

// device-coherent (cross-XCD) async global->LDS: aux=17 = SC0|SC1
__device__ __forceinline__ void gload_lds16_cc(const void* g, void* l) {
  __builtin_amdgcn_global_load_lds(
      (const __attribute__((address_space(1))) unsigned int*)g,
      (__attribute__((address_space(3))) unsigned int*)l,
      16, 0, 17);
}

// ---- weight transpose+convert: W[1024][4096] f32 -> WT[4096][1024] bf16
__global__ void wtrans(const float* __restrict__ W, short* __restrict__ WT) {
  __shared__ float tile[32][33];
  const int tx = threadIdx.x, ty = threadIdx.y;
  const int n0 = blockIdx.x << 5, k0 = blockIdx.y << 5;
#pragma unroll
  for (int i = 0; i < 32; i += 8)
    tile[ty + i][tx] = W[(size_t)(k0 + ty + i) * G4 + n0 + tx];
  __syncthreads();
#pragma unroll
  for (int i = 0; i < 32; i += 8)
    WT[(size_t)(n0 + ty + i) * 1024 + k0 + tx] = (short)f2b(tile[tx][ty + i]);
}

// ---- f32 -> bf16 convert (x into the shared A buffer)
__global__ __launch_bounds__(256)
void conv_bf16(const float* __restrict__ in, unsigned short* __restrict__ out) {
  const size_t i = ((size_t)blockIdx.x * 256 + threadIdx.x) * 8;
  const floatx4 a = *(const floatx4*)(in + i);
  const floatx4 b = *(const floatx4*)(in + i + 4);
  short8 s;
#pragma unroll
  for (int e = 0; e < 4; ++e) { s[e] = (short)f2b(a[e]); s[4 + e] = (short)f2b(b[e]); }
  *(short8*)(out + i) = s;
}

struct FusedArgs {
  // scan (blocks 0..127): recurrence for chunk [t0,t1) reading bf16 xw
  const unsigned short* xw;
  const short* wt_hi;
  unsigned short* hbuf;    // [2][64*1024] bf16 ping-pong (coherent traffic)
  float* cbuf;             // [64*1024] f32 persistent cell state
  unsigned int* flags;     // [NBLK] u32 padded to 64B
  float* hs;               // [512][64][1024] f32 output
  unsigned short* hsb;     // shared bf16 buffer: x rows become h rows
  float* h_final;
  float* c_final;
  int t0, t1, wr_final;
  // gemm: bf16 xw for the NEXT chunk -> dst
  const short* A;          // bf16 [Mrows][1024]
  const short* BT;         // WT [4096][1024] bf16
  const float* bias;
  unsigned short* dst;
  int Mrows, genable;
};

// ---- scan body: 8 waves x 512 threads. Wave = (gate 0..3, uh 0..1): 16 gate
// cols, FULL K=1024 (breg[32] = 128 regs; fits 256-VGPR budget @512thr).
// h_t staged via LDS (one coherent read per block, shared), two-phase:
// half-0 spans first (vmcnt(2)+barrier), K on half-0 overlaps half-1 arrival.
__device__ __forceinline__ void scan_body(const FusedArgs& p, char* smem) {
  float* gsm = (float*)(smem + 32768);   // [4 gate][16 b][33] f32 = 8448B
  const int tid = threadIdx.x;
  const int wave = tid >> 6, lane = tid & 63;
  const int lr = lane & 15, lh = lane >> 4;
  const int gate = wave >> 1, uh = wave & 1;
  const int blk = blockIdx.x;
  const int g = blk >> 5;                // batch group 0..3
  const int ub_idx = blk & 31;           // unit-block within hidden dim
  const int gcol = (gate << 10) + ub_idx * UPB + (uh << 4) + lr;

  // ---- preload B fragments (W_hi, full K): 32 x short8 = 128 regs
  short8 breg[32];
  {
    const short* wp = p.wt_hi + (size_t)gcol * HID + (lh << 3);
#pragma unroll
    for (int kk = 0; kk < 32; ++kk) breg[kk] = *(const short8*)(wp + (kk << 5));
  }

  const int b_loc = tid >> 5, u_loc = tid & 31;   // 512 threads = 16b x 32u
  const int ci = ((g * GBS + b_loc) << 10) + ub_idx * UPB + u_loc;
  float creg = p.cbuf[ci];

  const int asw = lr & 7;
  const unsigned long long fad =
      (unsigned long long)(p.flags + ((size_t)(g * BPG) + (lane & 31)) * 16);

  for (int t = p.t0; t < p.t1; ++t) {
    // ---- xw prefetch BEFORE the poll: latency rides under the flag wait
    float xv[4];
#pragma unroll
    for (int r = 0; r < 4; ++r) {
      const size_t rowi = (size_t)(t - p.t0) * BS + g * GBS + (lh << 2) + r;
      xv[r] = b2f(p.xw[rowi * G4 + gcol]);
    }

    // ---- barrier-in: wait until the group has published h for step t
    if (t > 0 && wave == 0) {
      unsigned f0;
      for (;;) {
        asm volatile("global_load_dword %0, %1, off sc0 sc1\n\t"
                     "s_waitcnt vmcnt(0)"
                     : "=v"(f0) : "v"(fad) : "memory");
        if (__all(f0 >= (unsigned)t)) break;
        __builtin_amdgcn_s_sleep(1);
      }
    }
    __syncthreads();

    const unsigned short* hb = p.hbuf + (size_t)(t & 1) * (BS * HID) + (size_t)g * GBS * HID;
    unsigned short* hw = p.hbuf + (size_t)((t + 1) & 1) * (BS * HID) + (size_t)g * GBS * HID;

    // ---- stage group h_t (32KB) -> LDS: 4 gload_lds/wave, half-0 first
    {
      const int spans[4] = { 2 * wave, 2 * wave + 16, 2 * wave + 1, 2 * wave + 17 };
#pragma unroll
      for (int j = 0; j < 4; ++j) {
        const int i = spans[j];
        const int row = i >> 1, half = i & 1;
        const int chunk = ((half << 6) + lane) ^ (row & 7);
        gload_lds16_cc(hb + row * HID + (chunk << 3), smem + (i << 10));
      }
    }
    asm volatile("s_waitcnt vmcnt(2)" ::: "memory");   // half-0 spans landed
    __builtin_amdgcn_s_barrier();
    __builtin_amdgcn_sched_barrier(0);

    // ---- K loop first half (k 0..511) while half-1 is in flight
    floatx4 acc = {0.f, 0.f, 0.f, 0.f};
#pragma unroll
    for (int kk = 0; kk < 16; ++kk) {
      const int kc = (kk << 2) + lh;
      const short8 afr = *(const short8*)(smem + (lr << 11) + ((kc ^ asw) << 4));
      acc = __builtin_amdgcn_mfma_f32_16x16x32_bf16(afr, breg[kk], acc, 0, 0, 0);
    }
    asm volatile("s_waitcnt vmcnt(0)" ::: "memory");   // half-1 landed
    __builtin_amdgcn_s_barrier();
    __builtin_amdgcn_sched_barrier(0);
#pragma unroll
    for (int kk = 16; kk < 32; ++kk) {
      const int kc = (kk << 2) + lh;
      const short8 afr = *(const short8*)(smem + (lr << 11) + ((kc ^ asw) << 4));
      acc = __builtin_amdgcn_mfma_f32_16x16x32_bf16(afr, breg[kk], acc, 0, 0, 0);
    }

    // ---- gates to gsm (full sums — no kh exchange)
#pragma unroll
    for (int r = 0; r < 4; ++r) {
      const int b = (lh << 2) + r;
      gsm[((gate << 4) + b) * 33 + (uh << 4) + lr] = acc[r] + xv[r];
    }
    __syncthreads();

    // ---- elementwise update + paired coherent publish; hs/hsb deferred
    const int o = b_loc * 33 + u_loc;
    const float ig = gsm[o];
    const float fg = gsm[16 * 33 + o];
    const float gg2 = gsm[32 * 33 + o];
    const float og = gsm[48 * 33 + o];
    const float iv = 1.f / (1.f + __expf(-ig));
    const float fv = 1.f / (1.f + __expf(-fg));
    const float gv = tanhf(gg2);
    const float ov = 1.f / (1.f + __expf(-og));
    const float cn = fv * creg + iv * gv;
    creg = cn;
    const float hv = ov * tanhf(cn);
    const unsigned hv16 = (unsigned)f2b(hv);
    {
      const unsigned other = (unsigned)__shfl_xor((int)hv16, 1, 64);
      if ((u_loc & 1) == 0) {
        const unsigned val = (hv16 & 0xFFFFu) | (other << 16);
        const unsigned long long dst =
            (unsigned long long)(hw + (size_t)b_loc * HID + ub_idx * UPB + u_loc);
        asm volatile("global_store_dword %0, %1, off sc0 sc1"
                     :: "v"(dst), "v"(val) : "memory");
      }
    }
    asm volatile("s_waitcnt vmcnt(0)" ::: "memory");  // drain the publish
    __syncthreads();
    if (tid == 0) {
      const unsigned long long fdst = (unsigned long long)(p.flags + (size_t)blk * 16);
      const unsigned fval = (unsigned)(t + 1);
      asm volatile("global_store_dword %0, %1, off sc0 sc1"
                   :: "v"(fdst), "v"(fval) : "memory");
    }
    // hs (f32 out) + hsb (bf16 A-buffer) writes off the critical path
    {
      const size_t oidx = ((size_t)t * BS + g * GBS + b_loc) * HID + ub_idx * UPB + u_loc;
      p.hs[oidx] = hv;
      p.hsb[oidx] = (unsigned short)hv16;
      if (p.wr_final && t == SEQ - 1) { p.h_final[ci] = hv; p.c_final[ci] = cn; }
    }
  }
  p.cbuf[ci] = creg;
}

// ---- gemm body: 512 threads / 8 waves (4x2 wave grid of 32x64), bf16 A/B,
// 128x128 tile, software-pipelined staging (r10/r11-proven geometry).
__device__ __forceinline__ void gemm_body(const FusedArgs& p, char* smem,
                                          int bi, int gstride) {
  if (!p.genable) return;
  short* Al = (short*)smem;            // [128][40]
  short* Bl = (short*)(smem + 10240);  // [128][40]
  const int tid = threadIdx.x;
  const int wave = tid >> 6, lane = tid & 63;
  const int lr = lane & 15, lh = lane >> 4;
  const int wm = wave >> 1, wn = wave & 1;   // 4x2 waves: 32 rows x 64 cols
  const int nmt = p.Mrows >> 7;
  const int tot = nmt << 5;                  // nmt x 32 tiles of 128x128
  const int srow = tid >> 2, scol = (tid & 3) << 3;   // short8 per thread

  for (int tt = bi; tt < tot; tt += gstride) {
    const int m0 = (tt >> 5) << 7, n0 = (tt & 31) << 7;
    const short* aptr = p.A + (size_t)(m0 + srow) * 1024 + scol;
    const short* bptr = p.BT + (size_t)(n0 + srow) * 1024 + scol;
    floatx4 acc[2][4] = {};
    short8 pa = *(const short8*)aptr;
    short8 pb = *(const short8*)bptr;
    for (int it = 0; it < 32; ++it) {
      __syncthreads();
      *(short8*)&Al[srow * 40 + scol] = pa;
      *(short8*)&Bl[srow * 40 + scol] = pb;
      __syncthreads();
      if (it < 31) {
        pa = *(const short8*)(aptr + ((it + 1) << 5));
        pb = *(const short8*)(bptr + ((it + 1) << 5));
      }
      short8 af[2], bf[4];
#pragma unroll
      for (int mt = 0; mt < 2; ++mt)
        af[mt] = *(const short8*)&Al[(wm * 32 + mt * 16 + lr) * 40 + lh * 8];
#pragma unroll
      for (int nt = 0; nt < 4; ++nt)
        bf[nt] = *(const short8*)&Bl[(wn * 64 + nt * 16 + lr) * 40 + lh * 8];
#pragma unroll
      for (int mt = 0; mt < 2; ++mt)
#pragma unroll
        for (int nt = 0; nt < 4; ++nt)
          acc[mt][nt] = __builtin_amdgcn_mfma_f32_16x16x32_bf16(af[mt], bf[nt], acc[mt][nt], 0, 0, 0);
    }
#pragma unroll
    for (int nt = 0; nt < 4; ++nt) {
      const int gc = n0 + wn * 64 + nt * 16 + lr;
      const float bv = p.bias[gc];
#pragma unroll
      for (int mt = 0; mt < 2; ++mt)
#pragma unroll
        for (int r = 0; r < 4; ++r) {
          const int gr = m0 + wm * 32 + mt * 16 + (lh << 2) + r;
          p.dst[(size_t)gr * G4 + gc] = f2b(acc[mt][nt][r] + bv);
        }
    }
  }
}

// prologue: pure-gemm dispatch, 256 blocks (one per CU)
__global__ __launch_bounds__(512, 2)
void gemm_pre(FusedArgs p) {
  __shared__ __align__(16) char smem[84480];
  gemm_body(p, smem, blockIdx.x, 2 * NBLK);
}

// 256 blocks x 512 threads. LDS 82.5KB forces 1 block/CU:
// scan blocks (0..127) and gemm blocks (128..255) land on different CUs.
__global__ __launch_bounds__(512, 2)
void lstm_fused(FusedArgs p) {
  __shared__ __align__(16) char smem[84480];
  if (blockIdx.x < NBLK) scan_body(p, smem);
  else                   gemm_body(p, smem, blockIdx.x - NBLK, NBLK);
}

extern "C" void kernel_launch(void* const* d_in, const int* in_sizes, int n_in,
                              void* d_out, int out_size, void* d_ws, size_t ws_size,
                              hipStream_t stream) {
  const float* x    = (const float*)d_in[0];
  const float* Wii0 = (const float*)d_in[1];
  const float* Wii  = (const float*)d_in[2];
  const float* Whi  = (const float*)d_in[3];
  const float* bias = (const float*)d_in[4];
  float* out  = (float*)d_out;
  float* hs   = out;
  float* hfin = out + (size_t)SEQ * BS * HID;
  float* cfin = hfin + BS * HID;

  char* ws = (char*)d_ws;
  short* WT0 = (short*)ws;
  short* WT1 = WT0 + (size_t)G4 * 1024;
  short* WTh = WT1 + (size_t)G4 * 1024;
  unsigned short* hbuf = (unsigned short*)(WTh + (size_t)G4 * 1024);
  float* cbuf = (float*)(hbuf + 2 * BS * HID);
  unsigned int* flags = (unsigned int*)(cbuf + BS * HID);   // 128 * 64B
  unsigned short* xb = (unsigned short*)(flags + NBLK * 16); // shared x/h bf16
  char* tail = (char*)(xb + (size_t)SEQ * BS * HID);
  const size_t head = (size_t)(tail - ws);
  const size_t avail = (ws_size > head) ? ws_size - head : 0;
  const size_t perT = (size_t)BS * G4 * 2;   // 512 KiB per timestep (bf16)

  int chunk;
  if      (avail >= 2 * 128 * perT) chunk = 128;
  else if (avail >= 2 * 64  * perT) chunk = 64;
  else if (avail >= 2 * 32  * perT) chunk = 32;
  else                              chunk = 8;
  const size_t chunkBytes = (size_t)chunk * perT;
  unsigned short* xwbuf[2] = { (unsigned short*)tail,
                               (unsigned short*)(tail + chunkBytes) };
  const int nc = SEQ / chunk;

  wtrans<<<dim3(128, 32), dim3(32, 8), 0, stream>>>(Wii0, WT0);
  wtrans<<<dim3(128, 32), dim3(32, 8), 0, stream>>>(Wii, WT1);
  wtrans<<<dim3(128, 32), dim3(32, 8), 0, stream>>>(Whi, WTh);
  conv_bf16<<<dim3((SEQ * BS * HID) / (256 * 8)), dim3(256), 0, stream>>>(x, xb);

  for (int layer = 0; layer < 2; ++layer) {
    hipMemsetAsync(hbuf, 0, 2 * BS * HID * sizeof(unsigned short), stream);
    hipMemsetAsync(cbuf, 0, BS * HID * sizeof(float), stream);
    hipMemsetAsync(flags, 0, NBLK * 16 * sizeof(unsigned int), stream);

    if (layer == 0) {  // prologue: only xw chunk not hidden behind a scan
      FusedArgs pa = {};
      pa.A = (const short*)xb;
      pa.BT = WT0;
      pa.bias = bias;
      pa.dst = xwbuf[0];
      pa.Mrows = chunk * BS;
      pa.genable = 1;
      gemm_pre<<<dim3(2 * NBLK), dim3(512), 0, stream>>>(pa);
    }

    for (int c = 0; c < nc; ++c) {
      FusedArgs fa;
      fa.xw = xwbuf[c & 1];
      fa.wt_hi = WTh;
      fa.hbuf = hbuf;
      fa.cbuf = cbuf;
      fa.flags = flags;
      fa.hs = hs;
      fa.hsb = xb;
      fa.h_final = layer ? hfin : nullptr;
      fa.c_final = layer ? cfin : nullptr;
      fa.t0 = c * chunk;
      fa.t1 = (c + 1) * chunk;
      fa.wr_final = layer;
      // producer: bf16 xw for the next chunk (wraps to next layer's first).
      fa.bias = bias;
      fa.dst = xwbuf[(c + 1) & 1];
      fa.Mrows = chunk * BS;
      const int nxt = ((c + 1) % nc) * chunk * BS;
      fa.A = (const short*)(xb + (size_t)nxt * HID);
      fa.BT = (layer == 0 && c < nc - 1) ? WT0 : WT1;
      fa.genable = !(layer == 1 && c == nc - 1);
      void* args[] = { &fa };
      hipLaunchCooperativeKernel(reinterpret_cast<const void*>(&lstm_fused),
                                 dim3(2 * NBLK), dim3(512), args, 0u, stream);
    }
  }
}